// Round 6
// baseline (29.683 us; speedup 1.0000x reference)
//
#include <hip/hip_runtime.h>
#include <math.h>

#define UPL 16          // 1024 units / 64 lanes
#define NTH 512         // 8 waves: wave 0 walks, all fill
#define MAXRUNS 512

// ---------- DPP helpers ----------
// min/max: old=v, bound_ctrl=false (invalid lanes keep v — harmless for min/max)
#define DPPMV(v, ctrl) __int_as_float(__builtin_amdgcn_update_dpp( \
    __float_as_int(v), __float_as_int(v), (ctrl), 0xf, 0xf, false))

__device__ inline float wave_min64(float v) {
    v = fminf(v, DPPMV(v, 0x111));   // row_shr:1
    v = fminf(v, DPPMV(v, 0x112));   // row_shr:2
    v = fminf(v, DPPMV(v, 0x114));   // row_shr:4
    v = fminf(v, DPPMV(v, 0x118));   // row_shr:8
    v = fminf(v, DPPMV(v, 0x142));   // row_bcast:15
    v = fminf(v, DPPMV(v, 0x143));   // row_bcast:31 -> lane63 total
    return __int_as_float(__builtin_amdgcn_readlane(__float_as_int(v), 63));
}
__device__ inline float wave_max64(float v) {
    v = fmaxf(v, DPPMV(v, 0x111));
    v = fmaxf(v, DPPMV(v, 0x112));
    v = fmaxf(v, DPPMV(v, 0x114));
    v = fmaxf(v, DPPMV(v, 0x118));
    v = fmaxf(v, DPPMV(v, 0x142));
    v = fmaxf(v, DPPMV(v, 0x143));
    return __int_as_float(__builtin_amdgcn_readlane(__float_as_int(v), 63));
}

// fp64 sum: old=0, bound_ctrl=true (invalid lanes contribute +0.0) — exact
// single-coverage chain; lane 63 holds the wave total.
template<int CTRL>
__device__ inline double ddpp0(double v) {
    long long l = __double_as_longlong(v);
    int lo = __builtin_amdgcn_update_dpp(0, (int)(l & 0xffffffffLL), CTRL, 0xf, 0xf, true);
    int hi = __builtin_amdgcn_update_dpp(0, (int)(l >> 32),          CTRL, 0xf, 0xf, true);
    return __longlong_as_double(((long long)hi << 32) | (unsigned long long)(unsigned)lo);
}
__device__ inline double wave_dsum64(double v) {
    v += ddpp0<0x111>(v);
    v += ddpp0<0x112>(v);
    v += ddpp0<0x114>(v);
    v += ddpp0<0x118>(v);
    v += ddpp0<0x142>(v);
    v += ddpp0<0x143>(v);
    long long l = __double_as_longlong(v);
    int lo = __builtin_amdgcn_readlane((int)(l & 0xffffffffLL), 63);
    int hi = __builtin_amdgcn_readlane((int)(l >> 32), 63);
    return __longlong_as_double(((long long)hi << 32) | (unsigned long long)(unsigned)lo);
}

// x_m = xs + delta * 2^(m*L2).  Series (expm1) path avoids cancellation vs a
// distant fixed point; identical expression in walk and fill => exact continuity.
__device__ inline double geo_val(double xs, double delta, double L2, double m) {
    double t = m * L2;
    if (fabs(t) < 0.043) {
        double e = t * 0.6931471805599453094;     // t*ln2, |e|<0.03
        double g = e * (1.0 + e * (0.5 + e * (1.0/6.0 + e * (1.0/24.0 + e * (1.0/120.0 + e * (1.0/720.0))))));
        return (xs + delta) + delta * g;
    }
    return xs + delta * (double)exp2f((float)t);
}
__device__ inline double lin_val(double xst, double d, double m) { return fma(m, d, xst); }

__global__ __launch_bounds__(NTH) void euler_kernel(
    const float* __restrict__ x0p, const float* __restrict__ dtp,
    const float* __restrict__ W1, const float* __restrict__ b1,
    const float* __restrict__ W2, const float* __restrict__ b2p,
    float* __restrict__ out, int nt)
{
    __shared__ int    s_k0[MAXRUNS];
    __shared__ double s_p0[MAXRUNS], s_p1[MAXRUNS], s_p2[MAXRUNS];
    __shared__ unsigned char s_ln[MAXRUNS];
    __shared__ int s_nr, s_fe;

    const int tid = threadIdx.x;
    const float x0f = x0p[0];
    const float INFF = __builtin_huge_valf();

    if (tid < 64) {
        const int lane = tid;
        const float dtf = dtp[0], b2 = b2p[0];

        // ---- per-lane unit registers (float4 loads) + initial (A,B) at x0 ----
        float tk[UPL], da[UPL], dc[UPL];
        double accA = 0.0, accB = 0.0;
        const float4* W14 = (const float4*)W1;
        const float4* B14 = (const float4*)b1;
        const float4* W24 = (const float4*)W2;
        #pragma unroll
        for (int i = 0; i < UPL / 4; ++i) {
            float4 w1v = W14[i * 64 + lane];
            float4 b1v = B14[i * 64 + lane];
            float4 w2v = W24[i * 64 + lane];
            float w1a[4] = {w1v.x, w1v.y, w1v.z, w1v.w};
            float b1a[4] = {b1v.x, b1v.y, b1v.z, b1v.w};
            float w2a[4] = {w2v.x, w2v.y, w2v.z, w2v.w};
            #pragma unroll
            for (int j = 0; j < 4; ++j) {
                int idx = i * 4 + j;
                float w1 = w1a[j], bb = b1a[j], w2 = w2a[j];
                float a = w1 * w2, cc = bb * w2;
                float key, d_a, d_c;
                if (w1 > 0.0f)      { key = -bb / w1; d_a =  a; d_c =  cc; }
                else if (w1 < 0.0f) { key = -bb / w1; d_a = -a; d_c = -cc; accA += (double)a; accB += (double)cc; }
                else                { key = INFF;     d_a = 0.0f; d_c = 0.0f; accB += (double)(fmaxf(bb, 0.0f) * w2); }
                tk[idx] = key; da[idx] = d_a; dc[idx] = d_c;
                if (key <= x0f) { accA += (double)d_a; accB += (double)d_c; }
            }
        }
        double A = wave_dsum64(accA);
        double B = wave_dsum64(accB) + (double)b2;

        const double dt = (double)dtf;
        double x = (double)x0f;
        float  xf = x0f;
        int k = 0, r = 0, fend = 0;
        const int last = nt - 1;

        // ---- event walk: one iteration per segment-run ----
        while (k < last && r < MAXRUNS) {
            double eps = dt * A, d = dt * B;
            double v = eps * x + d;
            int remaining = last - k;
            int m, lin; double P0, P1, P2;

            if (v == 0.0) { lin = 1; P0 = x; P1 = 0.0; P2 = 0.0; m = remaining; }
            else {
                const bool up = (v > 0.0);
                // nearest breakpoint beyond xf in motion direction: tree + DPP
                float T;
                if (up) {
                    float q0 = INFF, q1 = INFF, q2 = INFF, q3 = INFF;
                    #pragma unroll
                    for (int i = 0; i < UPL; i += 4) {
                        q0 = fminf(q0, (tk[i    ] > xf) ? tk[i    ] : INFF);
                        q1 = fminf(q1, (tk[i + 1] > xf) ? tk[i + 1] : INFF);
                        q2 = fminf(q2, (tk[i + 2] > xf) ? tk[i + 2] : INFF);
                        q3 = fminf(q3, (tk[i + 3] > xf) ? tk[i + 3] : INFF);
                    }
                    T = wave_min64(fminf(fminf(q0, q1), fminf(q2, q3)));
                } else {
                    float q0 = -INFF, q1 = -INFF, q2 = -INFF, q3 = -INFF;
                    #pragma unroll
                    for (int i = 0; i < UPL; i += 4) {
                        q0 = fmaxf(q0, (tk[i    ] < xf) ? tk[i    ] : -INFF);
                        q1 = fmaxf(q1, (tk[i + 1] < xf) ? tk[i + 1] : -INFF);
                        q2 = fmaxf(q2, (tk[i + 2] < xf) ? tk[i + 2] : -INFF);
                        q3 = fmaxf(q3, (tk[i + 3] < xf) ? tk[i + 3] : -INFF);
                    }
                    T = wave_max64(fmaxf(fmaxf(q0, q1), fmaxf(q2, q3)));
                }
                const double Td = (double)T;

                if (eps == 0.0) {               // cold path (exact-zero slope)
                    lin = 1; P0 = x; P1 = d; P2 = 0.0;
                    if (isinf(T)) m = remaining;
                    else {
                        double mm = (Td - x) / d;
                        m = (mm < (double)remaining) ? ((mm < 1.0) ? 1 : (int)ceil(mm)) : remaining;
                        int g = 0;
                        while (m < remaining && g++ < 8) { double y = lin_val(P0, P1, (double)m);     if (up ? (y >= Td) : (y <= Td)) break; ++m; }
                        g = 0;
                        while (m > 1 && g++ < 8)         { double y = lin_val(P0, P1, (double)(m-1)); if (up ? (y >= Td) : (y <= Td)) --m; else break; }
                    }
                } else {
                    lin = 0;
                    // xs = -d/eps via rcp + 2 Newton (rel err ~1e-16)
                    double r0 = (double)__builtin_amdgcn_rcpf((float)eps);
                    r0 = r0 * (2.0 - eps * r0);
                    r0 = r0 * (2.0 - eps * r0);
                    double xs = -d * r0;
                    double delta = x - xs;
                    double L2 = eps * (1.0 - eps * (0.5 - eps * (1.0/3.0 - eps * 0.25)))
                              * 1.4426950408889634074;          // log2(1+eps)
                    P0 = xs; P1 = delta; P2 = L2;
                    if (isinf(T)) m = remaining;
                    else {
                        // fp32 first-crossing estimate (err << 8 steps)
                        float uf  = (float)(Td - x) * __builtin_amdgcn_rcpf((float)delta);
                        float mmf = __log2f(1.0f + uf) / (float)L2;
                        // NaN (ratio<=0: never exits) or beyond budget -> full run
                        if (!(mmf < (float)remaining + 8.0f)) m = remaining;
                        else {
                            float msf = mmf - 8.0f;
                            int mstart = (msf > 1.0f) ? (int)msf : 1;
                            m = 0;
                            bool firstTry = true;
                            #pragma unroll 1
                            for (int t = 0; t < 8 && m == 0; ++t) {
                                if (mstart >= remaining) { m = remaining; break; }
                                double y = geo_val(P0, P1, P2, (double)(mstart + lane));
                                bool crossed = up ? (y >= Td) : (y <= Td);
                                unsigned long long cm = __ballot(crossed);
                                if (cm) {
                                    int idx = __ffsll(cm) - 1;
                                    if (idx == 0 && mstart > 1 && firstTry) {
                                        // crossing may begin before the window: shift down once
                                        mstart = (mstart > 64) ? (mstart - 64) : 1;
                                        firstTry = false;
                                        continue;
                                    }
                                    int mcf = mstart + idx;
                                    m = (mcf < remaining) ? mcf : remaining;
                                } else {
                                    mstart += 64;      // expand upward (rare)
                                    firstTry = false;
                                }
                            }
                            if (m == 0) m = remaining;
                        }
                    }
                }
            }

            if (lane == 0) {
                s_k0[r] = k; s_ln[r] = (unsigned char)lin;
                s_p0[r] = P0; s_p1[r] = P1; s_p2[r] = P2;
            }
            ++r;
            double xn = lin ? lin_val(P0, P1, (double)m) : geo_val(P0, P1, P2, (double)m);
            k += m; fend = k;
            float xnf = (float)xn;

            if (k < last) {
                // flip units whose breakpoints lie in the crossed interval
                float sA = 0.0f, sB = 0.0f; int cnt = 0;
                bool upm = (xnf > xf);
                #pragma unroll
                for (int i = 0; i < UPL; ++i) {
                    float tv = tk[i];
                    bool in = upm ? (tv > xf && tv <= xnf) : (tv > xnf && tv <= xf);
                    if (in) { sA += da[i]; sB += dc[i]; ++cnt; }
                }
                unsigned long long msk = __ballot(cnt > 0);
                double dsA = 0.0, dsB = 0.0;
                while (msk) {
                    int l = __ffsll(msk) - 1;
                    msk &= (msk - 1);
                    dsA += (double)__shfl(sA, l);
                    dsB += (double)__shfl(sB, l);
                }
                if (upm) { A += dsA; B += dsB; } else { A -= dsA; B -= dsB; }
            }
            x = xn; xf = xnf;
        }

        // ---- fallback (run table exhausted — pathological only): serial, direct out ----
        while (k < last) {
            double eps = dt * A, d = dt * B;
            double xn = x + (eps * x + d);
            ++k;
            if (lane == 0) out[k] = (float)xn;
            float xnf = (float)xn;
            float sA = 0.0f, sB = 0.0f;
            bool upm = (xnf > xf);
            #pragma unroll
            for (int i = 0; i < UPL; ++i) {
                float tv = tk[i];
                bool in = upm ? (tv > xf && tv <= xnf) : (tv > xnf && tv <= xf);
                if (in) { sA += da[i]; sB += dc[i]; }
            }
            #pragma unroll
            for (int off = 32; off; off >>= 1) {
                sA += __shfl_xor(sA, off);
                sB += __shfl_xor(sB, off);
            }
            if (upm) { A += (double)sA; B += (double)sB; }
            else     { A -= (double)sA; B -= (double)sB; }
            x = xn; xf = xnf;
        }

        if (lane == 0) { s_nr = r; s_fe = fend; }
    }
    __syncthreads();

    // ---- parallel closed-form fill (all 512 threads) ----
    {
        const int nr = s_nr, fe = s_fe;
        for (int kk = tid; kk <= fe; kk += NTH) {
            if (kk == 0) { out[0] = x0f; continue; }
            int lo = 0, hi = nr - 1;
            while (lo < hi) {                    // largest r with k0[r] < kk
                int mid = (lo + hi + 1) >> 1;
                if (s_k0[mid] < kk) lo = mid; else hi = mid - 1;
            }
            double m = (double)(kk - s_k0[lo]);
            double vv = s_ln[lo] ? lin_val(s_p0[lo], s_p1[lo], m)
                                 : geo_val(s_p0[lo], s_p1[lo], s_p2[lo], m);
            out[kk] = (float)vv;
        }
    }
}

extern "C" void kernel_launch(void* const* d_in, const int* in_sizes, int n_in,
                              void* d_out, int out_size, void* d_ws, size_t ws_size,
                              hipStream_t stream) {
    const float* x0 = (const float*)d_in[0];
    const float* dt = (const float*)d_in[1];
    const float* W1 = (const float*)d_in[3];
    const float* b1 = (const float*)d_in[4];
    const float* W2 = (const float*)d_in[5];
    const float* b2 = (const float*)d_in[6];
    float* out = (float*)d_out;
    const int nt = out_size;
    euler_kernel<<<1, NTH, 0, stream>>>(x0, dt, W1, b1, W2, b2, out, nt);
}

// Round 7
// 25.673 us; speedup vs baseline: 1.1562x; 1.1562x over previous
//
#include <hip/hip_runtime.h>
#include <math.h>

#define UPL 16          // 1024 units / 64 lanes
#define NTH 512         // 8 waves: wave 0 walks, all fill
#define MAXRUNS 512
#define LOG2E 1.4426950408889634074

// ---------- DPP helpers ----------
#define DPPMV(v, ctrl) __int_as_float(__builtin_amdgcn_update_dpp( \
    __float_as_int(v), __float_as_int(v), (ctrl), 0xf, 0xf, false))

__device__ inline float wave_min64(float v) {
    v = fminf(v, DPPMV(v, 0x111));   // row_shr:1
    v = fminf(v, DPPMV(v, 0x112));   // row_shr:2
    v = fminf(v, DPPMV(v, 0x114));   // row_shr:4
    v = fminf(v, DPPMV(v, 0x118));   // row_shr:8
    v = fminf(v, DPPMV(v, 0x142));   // row_bcast:15
    v = fminf(v, DPPMV(v, 0x143));   // row_bcast:31 -> lane63 total
    return __int_as_float(__builtin_amdgcn_readlane(__float_as_int(v), 63));
}
__device__ inline float wave_max64(float v) {
    v = fmaxf(v, DPPMV(v, 0x111));
    v = fmaxf(v, DPPMV(v, 0x112));
    v = fmaxf(v, DPPMV(v, 0x114));
    v = fmaxf(v, DPPMV(v, 0x118));
    v = fmaxf(v, DPPMV(v, 0x142));
    v = fmaxf(v, DPPMV(v, 0x143));
    return __int_as_float(__builtin_amdgcn_readlane(__float_as_int(v), 63));
}

// fp64 sum: old=0, bound_ctrl=true — exact single-coverage; lane63 total.
template<int CTRL>
__device__ inline double ddpp0(double v) {
    long long l = __double_as_longlong(v);
    int lo = __builtin_amdgcn_update_dpp(0, (int)(l & 0xffffffffLL), CTRL, 0xf, 0xf, true);
    int hi = __builtin_amdgcn_update_dpp(0, (int)(l >> 32),          CTRL, 0xf, 0xf, true);
    return __longlong_as_double(((long long)hi << 32) | (unsigned long long)(unsigned)lo);
}
__device__ inline double wave_dsum64(double v) {
    v += ddpp0<0x111>(v);
    v += ddpp0<0x112>(v);
    v += ddpp0<0x114>(v);
    v += ddpp0<0x118>(v);
    v += ddpp0<0x142>(v);
    v += ddpp0<0x143>(v);
    long long l = __double_as_longlong(v);
    int lo = __builtin_amdgcn_readlane((int)(l & 0xffffffffLL), 63);
    int hi = __builtin_amdgcn_readlane((int)(l >> 32), 63);
    return __longlong_as_double(((long long)hi << 32) | (unsigned long long)(unsigned)lo);
}

// 1/v: fp32 rcp seed + 2 fp64 Newton (rel err ~1e-16). Estimates only.
__device__ inline double nrecip(double v) {
    double r = (double)__builtin_amdgcn_rcpf((float)v);
    r = r * (2.0 - v * r);
    r = r * (2.0 - v * r);
    return r;
}

// x_m = xs + delta * 2^(m*L2).  expm1-series path avoids cancellation vs a
// distant fixed point; identical expression in walk and fill => exact continuity.
__device__ inline double geo_val(double xs, double delta, double L2, double m) {
    double t = m * L2;
    if (fabs(t) < 0.043) {
        double e = t * 0.6931471805599453094;     // t*ln2
        double g = e * (1.0 + e * (0.5 + e * (1.0/6.0 + e * (1.0/24.0 + e * (1.0/120.0 + e * (1.0/720.0))))));
        return (xs + delta) + delta * g;
    }
    return xs + delta * (double)exp2f((float)t);
}
__device__ inline double lin_val(double xst, double d, double m) { return fma(m, d, xst); }

__global__ __launch_bounds__(NTH) void euler_kernel(
    const float* __restrict__ x0p, const float* __restrict__ dtp,
    const float* __restrict__ W1, const float* __restrict__ b1,
    const float* __restrict__ W2, const float* __restrict__ b2p,
    float* __restrict__ out, int nt)
{
    __shared__ int    s_k0[MAXRUNS];
    __shared__ double s_p0[MAXRUNS], s_p1[MAXRUNS], s_p2[MAXRUNS];
    __shared__ unsigned char s_ln[MAXRUNS];
    __shared__ int s_nr, s_fe;

    const int tid = threadIdx.x;
    const float x0f = x0p[0];
    const float INFF = __builtin_huge_valf();

    if (tid < 64) {
        const int lane = tid;
        const float dtf = dtp[0], b2 = b2p[0];

        // ---- per-lane unit registers (float4 loads) + initial (A,B) at x0 ----
        float tk[UPL], da[UPL], dc[UPL];
        double accA = 0.0, accB = 0.0;
        const float4* W14 = (const float4*)W1;
        const float4* B14 = (const float4*)b1;
        const float4* W24 = (const float4*)W2;
        #pragma unroll
        for (int i = 0; i < UPL / 4; ++i) {
            float4 w1v = W14[i * 64 + lane];
            float4 b1v = B14[i * 64 + lane];
            float4 w2v = W24[i * 64 + lane];
            float w1a[4] = {w1v.x, w1v.y, w1v.z, w1v.w};
            float b1a[4] = {b1v.x, b1v.y, b1v.z, b1v.w};
            float w2a[4] = {w2v.x, w2v.y, w2v.z, w2v.w};
            #pragma unroll
            for (int j = 0; j < 4; ++j) {
                int idx = i * 4 + j;
                float w1 = w1a[j], bb = b1a[j], w2 = w2a[j];
                float a = w1 * w2, cc = bb * w2;
                float key, d_a, d_c;
                if (w1 > 0.0f)      { key = -bb / w1; d_a =  a; d_c =  cc; }
                else if (w1 < 0.0f) { key = -bb / w1; d_a = -a; d_c = -cc; accA += (double)a; accB += (double)cc; }
                else                { key = INFF;     d_a = 0.0f; d_c = 0.0f; accB += (double)(fmaxf(bb, 0.0f) * w2); }
                tk[idx] = key; da[idx] = d_a; dc[idx] = d_c;
                if (key <= x0f) { accA += (double)d_a; accB += (double)d_c; }
            }
        }
        double A = wave_dsum64(accA);
        double B = wave_dsum64(accB) + (double)b2;

        const double dt = (double)dtf;
        double x = (double)x0f;
        float  xf = x0f;
        int k = 0, r = 0, fend = 0;
        const int last = nt - 1;

        // ---- initial straddling-breakpoint prefetch at xf ----
        float T_up, T_dn;
        {
            float nu = INFF, nd = -INFF;
            #pragma unroll
            for (int i = 0; i < UPL; ++i) {
                float tv = tk[i];
                nu = fminf(nu, (tv > xf) ? tv : INFF);
                nd = fmaxf(nd, (tv < xf) ? tv : -INFF);
            }
            T_up = wave_min64(nu);
            T_dn = wave_max64(nd);
        }

        // ---- event walk: one iteration per segment-run ----
        while (k < last && r < MAXRUNS) {
            double eps = dt * A, d = dt * B;
            double v = eps * x + d;
            int remaining = last - k;
            int m, lin; double P0, P1, P2, xn;

            if (v == 0.0) {
                lin = 1; P0 = x; P1 = 0.0; P2 = 0.0; m = remaining; xn = x;
            } else {
                const bool up = (v > 0.0);
                const float T = up ? T_up : T_dn;       // prefetched
                const double Td = (double)T;

                if (eps == 0.0) {                        // cold path (exact-zero slope)
                    lin = 1; P0 = x; P1 = d; P2 = 0.0;
                    if (isinf(T)) m = remaining;
                    else {
                        double mm = (Td - x) * nrecip(d);
                        m = (mm < (double)remaining) ? ((mm < 1.0) ? 1 : (int)ceil(mm)) : remaining;
                        int g = 0;
                        while (m < remaining && g++ < 8) { double y = lin_val(P0, P1, (double)m);     if (up ? (y >= Td) : (y <= Td)) break; ++m; }
                        g = 0;
                        while (m > 1 && g++ < 8)         { double y = lin_val(P0, P1, (double)(m-1)); if (up ? (y >= Td) : (y <= Td)) --m; else break; }
                    }
                    xn = lin_val(P0, P1, (double)m);
                } else {
                    lin = 0;
                    double xs = -d * nrecip(eps);        // fixed point
                    double delta = x - xs;
                    double Ln = eps * (1.0 - eps * (0.5 - eps * (1.0/3.0 - eps * 0.25)));  // log1p(eps)
                    double L2 = Ln * LOG2E;
                    P0 = xs; P1 = delta; P2 = L2;

                    if (isinf(T)) {
                        m = remaining;
                        xn = geo_val(P0, P1, P2, (double)m);
                    } else {
                        // fp64 step-count estimate: mm = log1p(u)/log1p(eps)
                        double u = (Td - x) * nrecip(delta);
                        bool exits = (eps > 0.0) ? true : (u > -1.0 && u < 0.0);
                        if (!exits) m = remaining;
                        else {
                            double lrn = (fabs(u) <= 0.25)
                                ? u * (1.0 - u * (0.5 - u * (1.0/3.0 - u * (0.25 - u * (0.2 - u * (1.0/6.0))))))
                                : log(1.0 + u);
                            double mm = lrn * nrecip(Ln);
                            m = (mm < (double)remaining) ? ((mm < 1.0) ? 1 : (int)ceil(mm)) : remaining;
                        }
                        double ym = geo_val(P0, P1, P2, (double)m);
                        double yp = geo_val(P0, P1, P2, (double)(m - 1));   // ILP pair
                        int g = 0;
                        while (m < remaining && g++ < 8 && !(up ? (ym >= Td) : (ym <= Td))) {
                            ++m; yp = ym; ym = geo_val(P0, P1, P2, (double)m);
                        }
                        g = 0;
                        while (m > 1 && g++ < 8 && (up ? (yp >= Td) : (yp <= Td))) {
                            --m; ym = yp; yp = geo_val(P0, P1, P2, (double)(m - 1));
                        }
                        xn = ym;
                    }
                }
            }

            if (lane == 0) {
                s_k0[r] = k; s_ln[r] = (unsigned char)lin;
                s_p0[r] = P0; s_p1[r] = P1; s_p2[r] = P2;
            }
            ++r;
            k += m; fend = k;
            float xnf = (float)xn;

            if (k < last) {
                // fused: flip-scan over crossed interval + next-T prefetch at xnf
                float sA = 0.0f, sB = 0.0f; int cnt = 0;
                float nu = INFF, nd = -INFF;
                bool upm = (xnf > xf);
                #pragma unroll
                for (int i = 0; i < UPL; ++i) {
                    float tv = tk[i];
                    bool in = upm ? (tv > xf && tv <= xnf) : (tv > xnf && tv <= xf);
                    if (in) { sA += da[i]; sB += dc[i]; ++cnt; }
                    nu = fminf(nu, (tv > xnf) ? tv : INFF);
                    nd = fmaxf(nd, (tv < xnf) ? tv : -INFF);
                }
                T_up = wave_min64(nu);           // independent chains — overlap
                T_dn = wave_max64(nd);
                unsigned long long msk = __ballot(cnt > 0);
                double dsA = 0.0, dsB = 0.0;
                while (msk) {
                    int l = __ffsll(msk) - 1;
                    msk &= (msk - 1);
                    dsA += (double)__shfl(sA, l);
                    dsB += (double)__shfl(sB, l);
                }
                if (upm) { A += dsA; B += dsB; } else { A -= dsA; B -= dsB; }
            }
            x = xn; xf = xnf;
        }

        // ---- fallback (run table exhausted — pathological only): serial, direct out ----
        while (k < last) {
            double eps = dt * A, d = dt * B;
            double xn = x + (eps * x + d);
            ++k;
            if (lane == 0) out[k] = (float)xn;
            float xnf = (float)xn;
            float sA = 0.0f, sB = 0.0f;
            bool upm = (xnf > xf);
            #pragma unroll
            for (int i = 0; i < UPL; ++i) {
                float tv = tk[i];
                bool in = upm ? (tv > xf && tv <= xnf) : (tv > xnf && tv <= xf);
                if (in) { sA += da[i]; sB += dc[i]; }
            }
            #pragma unroll
            for (int off = 32; off; off >>= 1) {
                sA += __shfl_xor(sA, off);
                sB += __shfl_xor(sB, off);
            }
            if (upm) { A += (double)sA; B += (double)sB; }
            else     { A -= (double)sA; B -= (double)sB; }
            x = xn; xf = xnf;
        }

        if (lane == 0) { s_nr = r; s_fe = fend; }
    }
    __syncthreads();

    // ---- parallel closed-form fill (all 512 threads) ----
    {
        const int nr = s_nr, fe = s_fe;
        for (int kk = tid; kk <= fe; kk += NTH) {
            if (kk == 0) { out[0] = x0f; continue; }
            int lo = 0, hi = nr - 1;
            while (lo < hi) {                    // largest r with k0[r] < kk
                int mid = (lo + hi + 1) >> 1;
                if (s_k0[mid] < kk) lo = mid; else hi = mid - 1;
            }
            double m = (double)(kk - s_k0[lo]);
            double vv = s_ln[lo] ? lin_val(s_p0[lo], s_p1[lo], m)
                                 : geo_val(s_p0[lo], s_p1[lo], s_p2[lo], m);
            out[kk] = (float)vv;
        }
    }
}

extern "C" void kernel_launch(void* const* d_in, const int* in_sizes, int n_in,
                              void* d_out, int out_size, void* d_ws, size_t ws_size,
                              hipStream_t stream) {
    const float* x0 = (const float*)d_in[0];
    const float* dt = (const float*)d_in[1];
    const float* W1 = (const float*)d_in[3];
    const float* b1 = (const float*)d_in[4];
    const float* W2 = (const float*)d_in[5];
    const float* b2 = (const float*)d_in[6];
    float* out = (float*)d_out;
    const int nt = out_size;
    euler_kernel<<<1, NTH, 0, stream>>>(x0, dt, W1, b1, W2, b2, out, nt);
}